// Round 2
// baseline (303.352 us; speedup 1.0000x reference)
//
#include <hip/hip_runtime.h>
#include <stdint.h>

// HashEmbedder (Instant-NGP hash grid), MI355X gfx950.
// R8 -> R9 (resubmit; R9 bench hit GPUAcquisitionTimeout — no data).
// Attack the L2-request wall by REMOVING requests, not reordering them.
// k1 was request-rate-bound at ~0.58 req/cyc/CU (250K line-req/CU / 181us).
// Coarse levels have tiny distinct-corner sets: L0 17^3=4913, L1 21^3=9261,
// L2 26^3=17576 entries -> densify once (31,750 gathers total) and serve the
// 8-corner lookups from LDS (39/74/140 KB). That removes 24M of 64M L2
// requests. The gather kernel then covers levels 3..7 only, with blocks
// ordered level-major (bid/1024) so the whole chip works one 4MB table at a
// time -> every XCD L2 holds a replica of the active table (replication is
// MALL-served, ~free). Predicted: gather 181 -> ~115us, LDS path ~10-15us,
// total ~240us.

#define TABLE_SIZE (1u << 19)
#define TMASK (TABLE_SIZE - 1u)
#define P2 2654435761u
#define P3 805459861u

__device__ __forceinline__ float level_res(int l) {
    switch (l) {
        case 0: return 16.f; case 1: return 20.f; case 2: return 25.f;
        case 3: return 32.f; case 4: return 40.f; case 5: return 50.f;
        case 6: return 64.f; default: return 80.f;
    }
}

// ---------------- kernel 0: densify coarse hash tables --------------------
// dense[lv][(i*DIM + j)*DIM + k] = table[lv][(i ^ j*P2 ^ k*P3) & TMASK]
// Bit-identical values; only the indexing becomes dense. 31,750 entries total.
__global__ __launch_bounds__(256) void densify_kernel(
    const float* __restrict__ tables, float2* __restrict__ dense)
{
    const int lv = (int)blockIdx.y;
    int DIM, E, off;
    if (lv == 0)      { DIM = 17; E = 4913;  off = 0; }
    else if (lv == 1) { DIM = 21; E = 9261;  off = 4913; }
    else              { DIM = 26; E = 17576; off = 14174; }
    const int e = (int)blockIdx.x * 256 + (int)threadIdx.x;
    if (e >= E) return;
    const int d2 = DIM * DIM;
    const int i = e / d2;
    const int rem = e - i * d2;
    const int j = rem / DIM;
    const int k = rem - j * DIM;
    const uint32_t h = ((uint32_t)i ^ ((uint32_t)j * P2) ^ ((uint32_t)k * P3)) & TMASK;
    const float2* __restrict__ tab = (const float2*)tables + (size_t)lv * (size_t)TABLE_SIZE;
    dense[off + e] = tab[h];
}

// ---------------- kernel L: LDS-table embed for one coarse level ----------
// Stage the dense table into LDS (coalesced), then 8 corner lookups per point
// are ds_read_b64 (random -> ~4-way bank conflicts, cheap). Zero L2 gathers.
__global__ __launch_bounds__(256) void hash_embed_lds_kernel(
    const float* __restrict__ x, const float2* __restrict__ dense,
    float2* __restrict__ ws, int n, int lv, int DIM, int E, int doff, int ppt)
{
    extern __shared__ float2 lds[];
    for (int e = (int)threadIdx.x; e < E; e += 256) lds[e] = dense[doff + e];
    __syncthreads();

    const float R = level_res(lv);
    const float g = 1.0f / R;
    const int D2 = DIM * DIM;
    float2* __restrict__ wl = ws + (size_t)lv * (size_t)n;
    const int base = (int)blockIdx.x * (256 * ppt) + (int)threadIdx.x;

#pragma unroll 2
    for (int p = 0; p < ppt; ++p) {
        const int i = base + p * 256;
        if (i >= n) break;
        const float px = x[3*i+0], py = x[3*i+1], pz = x[3*i+2];
        const float cx = fminf(fmaxf(px, 0.0f), 1.0f);
        const float cy = fminf(fmaxf(py, 0.0f), 1.0f);
        const float cz = fminf(fmaxf(pz, 0.0f), 1.0f);
        // bx <= R-1 for any x < 1.0 (verified in float for R=16..25); min() is
        // a pure safety net for the x==1.0 boundary (result stays identical:
        // clamped cell + w=1 selects the same corner values).
        const int bx = min((int)floorf(cx * R), DIM - 2);
        const int by = min((int)floorf(cy * R), DIM - 2);
        const int bz = min((int)floorf(cz * R), DIM - 2);
        const float wx = (px - (float)bx * g) * R;
        const float wy = (py - (float)by * g) * R;
        const float wz = (pz - (float)bz * g) * R;
        const int c = (bx * DIM + by) * DIM + bz;
        const float2 e000 = lds[c];
        const float2 e001 = lds[c + 1];
        const float2 e010 = lds[c + DIM];
        const float2 e011 = lds[c + DIM + 1];
        const float2 e100 = lds[c + D2];
        const float2 e101 = lds[c + D2 + 1];
        const float2 e110 = lds[c + D2 + DIM];
        const float2 e111 = lds[c + D2 + DIM + 1];
        const float omx = 1.0f - wx, omy = 1.0f - wy, omz = 1.0f - wz;
        const float c00a = e000.x*omx + e100.x*wx, c00b = e000.y*omx + e100.y*wx;
        const float c01a = e001.x*omx + e101.x*wx, c01b = e001.y*omx + e101.y*wx;
        const float c10a = e010.x*omx + e110.x*wx, c10b = e010.y*omx + e110.y*wx;
        const float c11a = e011.x*omx + e111.x*wx, c11b = e011.y*omx + e111.y*wx;
        const float c0a = c00a*omy + c10a*wy, c0b = c00b*omy + c10b*wy;
        const float c1a = c01a*omy + c11a*wy, c1b = c01b*omy + c11b*wy;
        float2 r;
        r.x = c0a*omz + c1a*wz;
        r.y = c0b*omz + c1b*wz;
        wl[i] = r;
    }
}

// ---------------- kernel 1: gather-path embed (levels lv_base..7) ---------
// Blocks are level-major: level = lv_base + bid/bpl. In-order dispatch means
// all XCDs work the SAME level concurrently; each XCD L2 caches a replica of
// the active 4MB table (replication served from Infinity Cache).
__global__ __launch_bounds__(256, 4) void hash_embed_soa_kernel(
    const float* __restrict__ x, const float* __restrict__ tables,
    float2* __restrict__ ws, int n, int lv_base, int bpl)
{
    const int bid = (int)blockIdx.x;
    const int q = bid / bpl;
    const int l = lv_base + q;
    const int pb = bid - q * bpl;
    const int base = pb * 1024 + (int)threadIdx.x;
    if (base >= n) return;

    const float R = level_res(l);
    const float g = 1.0f / R;
    const float2* __restrict__ tab =
        (const float2*)(tables) + (size_t)l * (size_t)TABLE_SIZE;

    const int i0 = base, i1 = base + 256, i2 = base + 512, i3 = base + 768;

    const float px0 = x[3*i0+0], py0 = x[3*i0+1], pz0 = x[3*i0+2];
    const float px1 = x[3*i1+0], py1 = x[3*i1+1], pz1 = x[3*i1+2];
    const float px2 = x[3*i2+0], py2 = x[3*i2+1], pz2 = x[3*i2+2];
    const float px3 = x[3*i3+0], py3 = x[3*i3+1], pz3 = x[3*i3+2];

#define PREP(k) \
    const float cx##k = fminf(fmaxf(px##k, 0.0f), 1.0f); \
    const float cy##k = fminf(fmaxf(py##k, 0.0f), 1.0f); \
    const float cz##k = fminf(fmaxf(pz##k, 0.0f), 1.0f); \
    const int bx##k = (int)floorf(cx##k * R); \
    const int by##k = (int)floorf(cy##k * R); \
    const int bz##k = (int)floorf(cz##k * R); \
    const float wx##k = (px##k - (float)bx##k * g) * R; \
    const float wy##k = (py##k - (float)by##k * g) * R; \
    const float wz##k = (pz##k - (float)bz##k * g) * R; \
    const uint32_t hx0##k = (uint32_t)bx##k; \
    const uint32_t hx1##k = hx0##k + 1u; \
    const uint32_t hy0##k = (uint32_t)by##k * P2; \
    const uint32_t hy1##k = hy0##k + P2; \
    const uint32_t hz0##k = (uint32_t)bz##k * P3; \
    const uint32_t hz1##k = hz0##k + P3;

    PREP(0) PREP(1) PREP(2) PREP(3)

#define GATHER(k) \
    const float2 e0##k = tab[(hx0##k ^ hy0##k ^ hz0##k) & TMASK]; \
    const float2 e1##k = tab[(hx0##k ^ hy0##k ^ hz1##k) & TMASK]; \
    const float2 e2##k = tab[(hx0##k ^ hy1##k ^ hz0##k) & TMASK]; \
    const float2 e3##k = tab[(hx0##k ^ hy1##k ^ hz1##k) & TMASK]; \
    const float2 e4##k = tab[(hx1##k ^ hy0##k ^ hz0##k) & TMASK]; \
    const float2 e5##k = tab[(hx1##k ^ hy0##k ^ hz1##k) & TMASK]; \
    const float2 e6##k = tab[(hx1##k ^ hy1##k ^ hz0##k) & TMASK]; \
    const float2 e7##k = tab[(hx1##k ^ hy1##k ^ hz1##k) & TMASK];

    GATHER(0) GATHER(1) GATHER(2) GATHER(3)

#define INTERP(k, dst) { \
    const float omx = 1.0f - wx##k, omy = 1.0f - wy##k, omz = 1.0f - wz##k; \
    const float c00a = e0##k.x * omx + e4##k.x * wx##k; \
    const float c00b = e0##k.y * omx + e4##k.y * wx##k; \
    const float c01a = e1##k.x * omx + e5##k.x * wx##k; \
    const float c01b = e1##k.y * omx + e5##k.y * wx##k; \
    const float c10a = e2##k.x * omx + e6##k.x * wx##k; \
    const float c10b = e2##k.y * omx + e6##k.y * wx##k; \
    const float c11a = e3##k.x * omx + e7##k.x * wx##k; \
    const float c11b = e3##k.y * omx + e7##k.y * wx##k; \
    const float c0a = c00a * omy + c10a * wy##k; \
    const float c0b = c00b * omy + c10b * wy##k; \
    const float c1a = c01a * omy + c11a * wy##k; \
    const float c1b = c01b * omy + c11b * wy##k; \
    dst.x = c0a * omz + c1a * wz##k; \
    dst.y = c0b * omz + c1b * wz##k; }

    float2 r0, r1, r2, r3;
    INTERP(0, r0) INTERP(1, r1) INTERP(2, r2) INTERP(3, r3)

    float2* __restrict__ wl = ws + (size_t)l * (size_t)n;
    wl[i0] = r0;
    wl[i1] = r1;
    wl[i2] = r2;
    wl[i3] = r3;
}

// ---------------- kernel 2: SoA -> AoS transpose (register-only) ----------
__global__ __launch_bounds__(256) void soa_to_aos_kernel(
    const float2* __restrict__ ws, float* __restrict__ out, int n)
{
    const int i = blockIdx.x * 256 + threadIdx.x;
    if (i >= n) return;

    const float2 v0 = ws[0 * (size_t)n + i];
    const float2 v1 = ws[1 * (size_t)n + i];
    const float2 v2 = ws[2 * (size_t)n + i];
    const float2 v3 = ws[3 * (size_t)n + i];
    const float2 v4 = ws[4 * (size_t)n + i];
    const float2 v5 = ws[5 * (size_t)n + i];
    const float2 v6 = ws[6 * (size_t)n + i];
    const float2 v7 = ws[7 * (size_t)n + i];

    float4* __restrict__ op = (float4*)(out + (size_t)i * 16);
    op[0] = make_float4(v0.x, v0.y, v1.x, v1.y);
    op[1] = make_float4(v2.x, v2.y, v3.x, v3.y);
    op[2] = make_float4(v4.x, v4.y, v5.x, v5.y);
    op[3] = make_float4(v6.x, v6.y, v7.x, v7.y);
}

// ---------------- fallback (ws too small): monolithic ---------------------
__global__ __launch_bounds__(256) void hash_embed_mono_kernel(
    const float* __restrict__ x, const float* __restrict__ tables,
    float* __restrict__ out, int n)
{
    const int i = blockIdx.x * 256 + threadIdx.x;
    if (i >= n) return;
    const float px = x[3*i+0], py = x[3*i+1], pz = x[3*i+2];
    const float cx = fminf(fmaxf(px, 0.0f), 1.0f);
    const float cy = fminf(fmaxf(py, 0.0f), 1.0f);
    const float cz = fminf(fmaxf(pz, 0.0f), 1.0f);
    const float resf[8] = {16.f,20.f,25.f,32.f,40.f,50.f,64.f,80.f};
    float o[16];
#pragma unroll
    for (int l = 0; l < 8; ++l) {
        const float R = resf[l], g = 1.0f / R;
        const int bx = (int)floorf(cx*R), by = (int)floorf(cy*R), bz = (int)floorf(cz*R);
        const float wx = (px - bx*g)*R, wy = (py - by*g)*R, wz = (pz - bz*g)*R;
        const uint32_t hx0 = (uint32_t)bx, hx1 = hx0+1u;
        const uint32_t hy0 = (uint32_t)by*P2, hy1 = hy0+P2;
        const uint32_t hz0 = (uint32_t)bz*P3, hz1 = hz0+P3;
        const float2* tab = (const float2*)(tables) + (size_t)l*(size_t)TABLE_SIZE;
        const float2 e000 = tab[(hx0^hy0^hz0)&TMASK], e001 = tab[(hx0^hy0^hz1)&TMASK];
        const float2 e010 = tab[(hx0^hy1^hz0)&TMASK], e011 = tab[(hx0^hy1^hz1)&TMASK];
        const float2 e100 = tab[(hx1^hy0^hz0)&TMASK], e101 = tab[(hx1^hy0^hz1)&TMASK];
        const float2 e110 = tab[(hx1^hy1^hz0)&TMASK], e111 = tab[(hx1^hy1^hz1)&TMASK];
        const float omx = 1.f-wx, omy = 1.f-wy, omz = 1.f-wz;
        const float c00a = e000.x*omx + e100.x*wx, c00b = e000.y*omx + e100.y*wx;
        const float c01a = e001.x*omx + e101.x*wx, c01b = e001.y*omx + e101.y*wx;
        const float c10a = e010.x*omx + e110.x*wx, c10b = e010.y*omx + e110.y*wx;
        const float c11a = e011.x*omx + e111.x*wx, c11b = e011.y*omx + e111.y*wx;
        const float c0a = c00a*omy + c10a*wy, c0b = c00b*omy + c10b*wy;
        const float c1a = c01a*omy + c11a*wy, c1b = c01b*omy + c11b*wy;
        o[2*l+0] = c0a*omz + c1a*wz;
        o[2*l+1] = c0b*omz + c1b*wz;
    }
    float4* op = (float4*)(out + (size_t)i * 16);
    op[0] = make_float4(o[0],o[1],o[2],o[3]);
    op[1] = make_float4(o[4],o[5],o[6],o[7]);
    op[2] = make_float4(o[8],o[9],o[10],o[11]);
    op[3] = make_float4(o[12],o[13],o[14],o[15]);
}

extern "C" void kernel_launch(void* const* d_in, const int* in_sizes, int n_in,
                              void* d_out, int out_size, void* d_ws, size_t ws_size,
                              hipStream_t stream) {
    const float* x = (const float*)d_in[0];
    const float* tables = (const float*)d_in[1];
    float* out = (float*)d_out;
    const int n = in_sizes[0] / 3;  // 1048576 points

    const size_t ws_needed = (size_t)8 * (size_t)n * sizeof(float2);  // 64 MB
    if (ws_size < ws_needed) {
        hash_embed_mono_kernel<<<(n + 255) / 256, 256, 0, stream>>>(x, tables, out, n);
        return;
    }
    float2* ws = (float2*)d_ws;
    // Dense coarse tables live in the head of `out` (254 KB) — consumed by the
    // LDS kernels, then fully overwritten by soa_to_aos at the end.
    float2* dense = (float2*)out;

    // >64KB dynamic LDS needs opt-in. Cache the capability; degrade gracefully.
    static int nlds = -1;
    if (nlds < 0) {
        if (hipFuncSetAttribute((const void*)hash_embed_lds_kernel,
                hipFuncAttributeMaxDynamicSharedMemorySize, 140608) == hipSuccess)
            nlds = 3;   // levels 0,1,2 via LDS (39/74/140 KB)
        else if (hipFuncSetAttribute((const void*)hash_embed_lds_kernel,
                hipFuncAttributeMaxDynamicSharedMemorySize, 74088) == hipSuccess)
            nlds = 2;   // levels 0,1 via LDS
        else
            nlds = 1;   // level 0 only (39 KB fits default limit)
    }

    // k0: densify coarse tables (31,750 gathers total — noise)
    densify_kernel<<<dim3((17576 + 255) / 256, nlds), 256, 0, stream>>>(tables, dense);

    // LDS-path levels. ppt chosen so (blocks/CU × LDS) fits 160 KB:
    // L0: 39KB ×4 blocks/CU, L1: 74KB ×2, L2: 140KB ×1.
    static const int DIMt[3] = {17, 21, 26};
    static const int Et[3]   = {4913, 9261, 17576};
    static const int OFFt[3] = {0, 4913, 14174};
    static const int PPTt[3] = {4, 8, 16};
    for (int lv = 0; lv < nlds; ++lv) {
        const int ppb = 256 * PPTt[lv];
        const int grid = (n + ppb - 1) / ppb;
        hash_embed_lds_kernel<<<grid, 256, (size_t)Et[lv] * sizeof(float2), stream>>>(
            x, dense, ws, n, lv, DIMt[lv], Et[lv], OFFt[lv], PPTt[lv]);
    }

    // Gather-path levels nlds..7, level-major block order.
    const int bpl = (n + 1023) / 1024;
    const int nglv = 8 - nlds;
    hash_embed_soa_kernel<<<bpl * nglv, 256, 0, stream>>>(x, tables, ws, n, nlds, bpl);

    soa_to_aos_kernel<<<(n + 255) / 256, 256, 0, stream>>>(ws, out, n);
}

// Round 5
// 286.541 us; speedup vs baseline: 1.0587x; 1.0587x over previous
//
#include <hip/hip_runtime.h>
#include <stdint.h>

// HashEmbedder (Instant-NGP hash grid), MI355X gfx950.
// R9 -> R10 (3rd resubmit; benches hit GPUAcquisitionTimeout — never ran).
// R9 post-mortem: gather 181->123.5us (level-major + coarse-level
// removal CONFIRMED the per-CU request wall), but 3 LDS kernels cost ~18us
// each (4 waves/CU at 140KB LDS x 256 thr) and ate the win (303us total).
// R10: (a) LDS kernels at 1024 thr/block -> 16-32 waves/CU, ~5us each.
// (b) HALVE the gather request count: densify levels 3..7 into dense 3D
// tables with z-adjacent corner PAIRS packed in one aligned float4 ->
// 4 gathers/point/level instead of 8. Dense tables (16.9MB) built per call
// into the head of `out` (overwritten by the final transpose). Predicted:
// gather ~65-75us, total ~215-235us.

#define TABLE_SIZE (1u << 19)
#define TMASK (TABLE_SIZE - 1u)
#define P2 2654435761u
#define P3 805459861u

// Pair-table geometry per level l: R, DIMJ=R+1 (i,j in 0..R), DIMK=R
// (k in 0..R-1; entry k holds corners z=k and z=k+1), off4 = float4 offset.
// L0..L7 offsets: 0,4624,13444,30344,65192,132432,262482,532882 (tot 1057762)
#define PAIR_BYTES_OFF 262144  // pair region starts 256KB into `out`

__device__ __forceinline__ void level_geom(int l, float& R, int& DIMJ, int& DIMK, int& off4) {
    switch (l) {
        case 0: R=16.f; DIMJ=17; DIMK=16; off4=0;      break;
        case 1: R=20.f; DIMJ=21; DIMK=20; off4=4624;   break;
        case 2: R=25.f; DIMJ=26; DIMK=25; off4=13444;  break;
        case 3: R=32.f; DIMJ=33; DIMK=32; off4=30344;  break;
        case 4: R=40.f; DIMJ=41; DIMK=40; off4=65192;  break;
        case 5: R=50.f; DIMJ=51; DIMK=50; off4=132432; break;
        case 6: R=64.f; DIMJ=65; DIMK=64; off4=262482; break;
        default:R=80.f; DIMJ=81; DIMK=80; off4=532882; break;
    }
}

// ---------------- kernel 0a: densify coarse tables (float2, for LDS path) --
__global__ __launch_bounds__(256) void densify_kernel(
    const float* __restrict__ tables, float2* __restrict__ dense)
{
    const int lv = (int)blockIdx.y;
    int DIM, E, off;
    if (lv == 0)      { DIM = 17; E = 4913;  off = 0; }
    else if (lv == 1) { DIM = 21; E = 9261;  off = 4913; }
    else              { DIM = 26; E = 17576; off = 14174; }
    const int e = (int)blockIdx.x * 256 + (int)threadIdx.x;
    if (e >= E) return;
    const int d2 = DIM * DIM;
    const int i = e / d2;
    const int rem = e - i * d2;
    const int j = rem / DIM;
    const int k = rem - j * DIM;
    const uint32_t h = ((uint32_t)i ^ ((uint32_t)j * P2) ^ ((uint32_t)k * P3)) & TMASK;
    const float2* __restrict__ tab = (const float2*)tables + (size_t)lv * (size_t)TABLE_SIZE;
    dense[off + e] = tab[h];
}

// ---------------- kernel 0b: densify z-paired tables (float4, all levels) --
// pd[off4 + (i*DIMJ + j)*DIMK + k] = {tab[h(i,j,k)], tab[h(i,j,k+1)]}
__global__ __launch_bounds__(256) void densify_pairs_kernel(
    const float* __restrict__ tables, float4* __restrict__ pd)
{
    const int l = (int)blockIdx.y;
    float R; int DIMJ, DIMK, off4;
    level_geom(l, R, DIMJ, DIMK, off4);
    const int E = (DIMJ * DIMJ) * DIMK;
    const int e = (int)blockIdx.x * 256 + (int)threadIdx.x;
    if (e >= E) return;
    const int jk = DIMJ * DIMK;
    const int i = e / jk;
    const int rem = e - i * jk;
    const int j = rem / DIMK;
    const int k = rem - j * DIMK;
    const uint32_t hb = (uint32_t)i ^ ((uint32_t)j * P2);
    const uint32_t h0 = (hb ^ ((uint32_t)k * P3)) & TMASK;
    const uint32_t h1 = (hb ^ ((uint32_t)(k + 1) * P3)) & TMASK;
    const float2* __restrict__ tab = (const float2*)tables + (size_t)l * (size_t)TABLE_SIZE;
    const float2 a = tab[h0];
    const float2 b = tab[h1];
    pd[off4 + e] = make_float4(a.x, a.y, b.x, b.y);
}

// ---------------- kernel L: LDS-table embed for one coarse level ----------
// 1024 thr/block: L0 39KB x2wg/CU=32 waves, L1 74KB x2=32, L2 140KB x1=16.
__global__ __launch_bounds__(1024) void hash_embed_lds_kernel(
    const float* __restrict__ x, const float2* __restrict__ dense,
    float2* __restrict__ ws, int n, int lv, int DIM, int E, int doff, int ppt)
{
    extern __shared__ float2 lds[];
    for (int e = (int)threadIdx.x; e < E; e += 1024) lds[e] = dense[doff + e];
    __syncthreads();

    const float R = (lv == 0) ? 16.f : (lv == 1) ? 20.f : 25.f;
    const float g = 1.0f / R;
    const int D2 = DIM * DIM;
    const int bmax = DIM - 2;
    float2* __restrict__ wl = ws + (size_t)lv * (size_t)n;
    const int base = (int)blockIdx.x * (1024 * ppt) + (int)threadIdx.x;

#pragma unroll
    for (int p = 0; p < 4; ++p) {
        if (p >= ppt) break;
        const int i = base + p * 1024;
        if (i >= n) break;
        const float px = x[3*i+0], py = x[3*i+1], pz = x[3*i+2];
        const float cx = fminf(fmaxf(px, 0.0f), 1.0f);
        const float cy = fminf(fmaxf(py, 0.0f), 1.0f);
        const float cz = fminf(fmaxf(pz, 0.0f), 1.0f);
        const int bx = min((int)floorf(cx * R), bmax);
        const int by = min((int)floorf(cy * R), bmax);
        const int bz = min((int)floorf(cz * R), bmax);
        const float wx = (px - (float)bx * g) * R;
        const float wy = (py - (float)by * g) * R;
        const float wz = (pz - (float)bz * g) * R;
        const int c = (bx * DIM + by) * DIM + bz;
        const float2 e000 = lds[c];
        const float2 e001 = lds[c + 1];
        const float2 e010 = lds[c + DIM];
        const float2 e011 = lds[c + DIM + 1];
        const float2 e100 = lds[c + D2];
        const float2 e101 = lds[c + D2 + 1];
        const float2 e110 = lds[c + D2 + DIM];
        const float2 e111 = lds[c + D2 + DIM + 1];
        const float omx = 1.0f - wx, omy = 1.0f - wy, omz = 1.0f - wz;
        const float c00a = e000.x*omx + e100.x*wx, c00b = e000.y*omx + e100.y*wx;
        const float c01a = e001.x*omx + e101.x*wx, c01b = e001.y*omx + e101.y*wx;
        const float c10a = e010.x*omx + e110.x*wx, c10b = e010.y*omx + e110.y*wx;
        const float c11a = e011.x*omx + e111.x*wx, c11b = e011.y*omx + e111.y*wx;
        const float c0a = c00a*omy + c10a*wy, c0b = c00b*omy + c10b*wy;
        const float c1a = c01a*omy + c11a*wy, c1b = c01b*omy + c11b*wy;
        float2 r;
        r.x = c0a*omz + c1a*wz;
        r.y = c0b*omz + c1b*wz;
        wl[i] = r;
    }
}

// ---------------- kernel 1: paired-gather embed (levels lv_base..7) -------
// 4 float4 gathers per point (z-pairs packed) instead of 8 float2 gathers.
// Level-major block order -> whole chip works one dense table at a time.
__global__ __launch_bounds__(256, 4) void hash_embed_pairs_kernel(
    const float* __restrict__ x, const float4* __restrict__ pd,
    float2* __restrict__ ws, int n, int lv_base, int bpl)
{
    const int bid = (int)blockIdx.x;
    const int q = bid / bpl;
    const int l = lv_base + q;
    const int pb = bid - q * bpl;
    const int base = pb * 1024 + (int)threadIdx.x;
    if (base >= n) return;

    float R; int DIMJ, DIMK, off4;
    level_geom(l, R, DIMJ, DIMK, off4);
    const float g = 1.0f / R;
    const int bmax = DIMK - 1;           // = R-1
    const int jk = DIMJ * DIMK;
    const float4* __restrict__ tab = pd + off4;

    const int i0 = base, i1 = base + 256, i2 = base + 512, i3 = base + 768;

    const float px0 = x[3*i0+0], py0 = x[3*i0+1], pz0 = x[3*i0+2];
    const float px1 = x[3*i1+0], py1 = x[3*i1+1], pz1 = x[3*i1+2];
    const float px2 = x[3*i2+0], py2 = x[3*i2+1], pz2 = x[3*i2+2];
    const float px3 = x[3*i3+0], py3 = x[3*i3+1], pz3 = x[3*i3+2];

#define PREP(k) \
    const float cx##k = fminf(fmaxf(px##k, 0.0f), 1.0f); \
    const float cy##k = fminf(fmaxf(py##k, 0.0f), 1.0f); \
    const float cz##k = fminf(fmaxf(pz##k, 0.0f), 1.0f); \
    const int bx##k = min((int)floorf(cx##k * R), bmax); \
    const int by##k = min((int)floorf(cy##k * R), bmax); \
    const int bz##k = min((int)floorf(cz##k * R), bmax); \
    const float wx##k = (px##k - (float)bx##k * g) * R; \
    const float wy##k = (py##k - (float)by##k * g) * R; \
    const float wz##k = (pz##k - (float)bz##k * g) * R; \
    const int c00##k = (bx##k * DIMJ + by##k) * DIMK + bz##k; \
    const int c01##k = c00##k + DIMK; \
    const int c10##k = c00##k + jk; \
    const int c11##k = c10##k + DIMK;

    PREP(0) PREP(1) PREP(2) PREP(3)

#define GATHER(k) \
    const float4 d00##k = tab[c00##k]; \
    const float4 d01##k = tab[c01##k]; \
    const float4 d10##k = tab[c10##k]; \
    const float4 d11##k = tab[c11##k];

    GATHER(0) GATHER(1) GATHER(2) GATHER(3)

    // d00={e000,e001} d01={e010,e011} d10={e100,e101} d11={e110,e111}
#define INTERP(k, dst) { \
    const float omx = 1.0f - wx##k, omy = 1.0f - wy##k, omz = 1.0f - wz##k; \
    const float c00a = d00##k.x * omx + d10##k.x * wx##k; \
    const float c00b = d00##k.y * omx + d10##k.y * wx##k; \
    const float c01a = d00##k.z * omx + d10##k.z * wx##k; \
    const float c01b = d00##k.w * omx + d10##k.w * wx##k; \
    const float c10a = d01##k.x * omx + d11##k.x * wx##k; \
    const float c10b = d01##k.y * omx + d11##k.y * wx##k; \
    const float c11a = d01##k.z * omx + d11##k.z * wx##k; \
    const float c11b = d01##k.w * omx + d11##k.w * wx##k; \
    const float c0a = c00a * omy + c10a * wy##k; \
    const float c0b = c00b * omy + c10b * wy##k; \
    const float c1a = c01a * omy + c11a * wy##k; \
    const float c1b = c01b * omy + c11b * wy##k; \
    dst.x = c0a * omz + c1a * wz##k; \
    dst.y = c0b * omz + c1b * wz##k; }

    float2 r0, r1, r2, r3;
    INTERP(0, r0) INTERP(1, r1) INTERP(2, r2) INTERP(3, r3)

    float2* __restrict__ wl = ws + (size_t)l * (size_t)n;
    wl[i0] = r0;
    wl[i1] = r1;
    wl[i2] = r2;
    wl[i3] = r3;
}

// ---------------- kernel 2: SoA -> AoS transpose (register-only) ----------
__global__ __launch_bounds__(256) void soa_to_aos_kernel(
    const float2* __restrict__ ws, float* __restrict__ out, int n)
{
    const int i = blockIdx.x * 256 + threadIdx.x;
    if (i >= n) return;

    const float2 v0 = ws[0 * (size_t)n + i];
    const float2 v1 = ws[1 * (size_t)n + i];
    const float2 v2 = ws[2 * (size_t)n + i];
    const float2 v3 = ws[3 * (size_t)n + i];
    const float2 v4 = ws[4 * (size_t)n + i];
    const float2 v5 = ws[5 * (size_t)n + i];
    const float2 v6 = ws[6 * (size_t)n + i];
    const float2 v7 = ws[7 * (size_t)n + i];

    float4* __restrict__ op = (float4*)(out + (size_t)i * 16);
    op[0] = make_float4(v0.x, v0.y, v1.x, v1.y);
    op[1] = make_float4(v2.x, v2.y, v3.x, v3.y);
    op[2] = make_float4(v4.x, v4.y, v5.x, v5.y);
    op[3] = make_float4(v6.x, v6.y, v7.x, v7.y);
}

// ---------------- fallback (ws too small): monolithic ---------------------
__global__ __launch_bounds__(256) void hash_embed_mono_kernel(
    const float* __restrict__ x, const float* __restrict__ tables,
    float* __restrict__ out, int n)
{
    const int i = blockIdx.x * 256 + threadIdx.x;
    if (i >= n) return;
    const float px = x[3*i+0], py = x[3*i+1], pz = x[3*i+2];
    const float cx = fminf(fmaxf(px, 0.0f), 1.0f);
    const float cy = fminf(fmaxf(py, 0.0f), 1.0f);
    const float cz = fminf(fmaxf(pz, 0.0f), 1.0f);
    const float resf[8] = {16.f,20.f,25.f,32.f,40.f,50.f,64.f,80.f};
    float o[16];
#pragma unroll
    for (int l = 0; l < 8; ++l) {
        const float R = resf[l], g = 1.0f / R;
        const int bx = (int)floorf(cx*R), by = (int)floorf(cy*R), bz = (int)floorf(cz*R);
        const float wx = (px - bx*g)*R, wy = (py - by*g)*R, wz = (pz - bz*g)*R;
        const uint32_t hx0 = (uint32_t)bx, hx1 = hx0+1u;
        const uint32_t hy0 = (uint32_t)by*P2, hy1 = hy0+P2;
        const uint32_t hz0 = (uint32_t)bz*P3, hz1 = hz0+P3;
        const float2* tab = (const float2*)(tables) + (size_t)l*(size_t)TABLE_SIZE;
        const float2 e000 = tab[(hx0^hy0^hz0)&TMASK], e001 = tab[(hx0^hy0^hz1)&TMASK];
        const float2 e010 = tab[(hx0^hy1^hz0)&TMASK], e011 = tab[(hx0^hy1^hz1)&TMASK];
        const float2 e100 = tab[(hx1^hy0^hz0)&TMASK], e101 = tab[(hx1^hy0^hz1)&TMASK];
        const float2 e110 = tab[(hx1^hy1^hz0)&TMASK], e111 = tab[(hx1^hy1^hz1)&TMASK];
        const float omx = 1.f-wx, omy = 1.f-wy, omz = 1.f-wz;
        const float c00a = e000.x*omx + e100.x*wx, c00b = e000.y*omx + e100.y*wx;
        const float c01a = e001.x*omx + e101.x*wx, c01b = e001.y*omx + e101.y*wx;
        const float c10a = e010.x*omx + e110.x*wx, c10b = e010.y*omx + e110.y*wx;
        const float c11a = e011.x*omx + e111.x*wx, c11b = e011.y*omx + e111.y*wx;
        const float c0a = c00a*omy + c10a*wy, c0b = c00b*omy + c10b*wy;
        const float c1a = c01a*omy + c11a*wy, c1b = c01b*omy + c11b*wy;
        o[2*l+0] = c0a*omz + c1a*wz;
        o[2*l+1] = c0b*omz + c1b*wz;
    }
    float4* op = (float4*)(out + (size_t)i * 16);
    op[0] = make_float4(o[0],o[1],o[2],o[3]);
    op[1] = make_float4(o[4],o[5],o[6],o[7]);
    op[2] = make_float4(o[8],o[9],o[10],o[11]);
    op[3] = make_float4(o[12],o[13],o[14],o[15]);
}

extern "C" void kernel_launch(void* const* d_in, const int* in_sizes, int n_in,
                              void* d_out, int out_size, void* d_ws, size_t ws_size,
                              hipStream_t stream) {
    const float* x = (const float*)d_in[0];
    const float* tables = (const float*)d_in[1];
    float* out = (float*)d_out;
    const int n = in_sizes[0] / 3;  // 1048576 points

    const size_t ws_needed = (size_t)8 * (size_t)n * sizeof(float2);  // 64 MB
    if (ws_size < ws_needed) {
        hash_embed_mono_kernel<<<(n + 255) / 256, 256, 0, stream>>>(x, tables, out, n);
        return;
    }
    float2* ws = (float2*)d_ws;
    // Scratch in `out` (fully overwritten by soa_to_aos at the end):
    //   [0, 254KB):        float2 coarse dense tables (LDS path)
    //   [256KB, ~17.2MB):  float4 z-paired dense tables (gather path)
    float2* dense = (float2*)out;
    float4* pd = (float4*)((char*)out + PAIR_BYTES_OFF);

    // >64KB dynamic LDS needs opt-in. Cache the capability; degrade gracefully.
    static int nlds = -1;
    if (nlds < 0) {
        if (hipFuncSetAttribute((const void*)hash_embed_lds_kernel,
                hipFuncAttributeMaxDynamicSharedMemorySize, 140608) == hipSuccess)
            nlds = 3;   // levels 0,1,2 via LDS (39/74/140 KB)
        else if (hipFuncSetAttribute((const void*)hash_embed_lds_kernel,
                hipFuncAttributeMaxDynamicSharedMemorySize, 74088) == hipSuccess)
            nlds = 2;   // levels 0,1 via LDS
        else
            nlds = 1;   // level 0 only (39 KB fits default limit)
    }

    // k0a: coarse float2 dense (31,750 gathers). k0b: paired float4 dense for
    // ALL levels (1.06M entries, 2.1M gathers ~= 1/30 of main kernel).
    densify_kernel<<<dim3((17576 + 255) / 256, nlds), 256, 0, stream>>>(tables, dense);
    densify_pairs_kernel<<<dim3((524880 + 255) / 256, 8), 256, 0, stream>>>(tables, pd);

    // LDS-path levels: 1024 thr/block; ppt so grid covers 256 CUs.
    static const int DIMt[3] = {17, 21, 26};
    static const int Et[3]   = {4913, 9261, 17576};
    static const int OFFt[3] = {0, 4913, 14174};
    static const int PPTt[3] = {2, 2, 4};   // grids: 512, 512, 256 blocks
    for (int lv = 0; lv < nlds; ++lv) {
        const int ppb = 1024 * PPTt[lv];
        const int grid = (n + ppb - 1) / ppb;
        hash_embed_lds_kernel<<<grid, 1024, (size_t)Et[lv] * sizeof(float2), stream>>>(
            x, dense, ws, n, lv, DIMt[lv], Et[lv], OFFt[lv], PPTt[lv]);
    }

    // Paired-gather levels nlds..7, level-major block order.
    const int bpl = (n + 1023) / 1024;
    const int nglv = 8 - nlds;
    hash_embed_pairs_kernel<<<bpl * nglv, 256, 0, stream>>>(x, pd, ws, n, nlds, bpl);

    soa_to_aos_kernel<<<(n + 255) / 256, 256, 0, stream>>>(ws, out, n);
}

// Round 6
// 264.388 us; speedup vs baseline: 1.1474x; 1.0838x over previous
//
#include <hip/hip_runtime.h>
#include <stdint.h>

// HashEmbedder (Instant-NGP hash grid), MI355X gfx950.
// R10 -> R11. R10 post-mortem: requests halved but pairs kernel only
// 123.5->119us; FETCH_SIZE 54->230MB. Diagnosis: L6 (4.33MB) and L7 (8.4MB)
// dense pair tables EXCEED the 4MB per-XCD L2 -> random gathers thrash L2
// (~2.5M misses x 128B == the measured FETCH). Pairing only pays when the
// table is L2-resident. R11: levels 3..6 keep pairs (0.56/1.08/2.08/4.33MB),
// level 7 reverts to the original 4MB hash table (exact L2 fit). Gather
// instructions: 4x4M + 8M = 24M vs R9's 40M@123.5us. Predicted: mixed kernel
// ~75-90us, FETCH ~60-90MB, total ~245-265us.

#define TABLE_SIZE (1u << 19)
#define TMASK (TABLE_SIZE - 1u)
#define P2 2654435761u
#define P3 805459861u

// Pair-table geometry per level l (0..6): R, DIMJ=R+1 (i,j in 0..R), DIMK=R
// (k in 0..R-1; entry k holds corners z=k and z=k+1), off4 = float4 offset.
// Offsets: L0:0 L1:4624 L2:13444 L3:30344 L4:65192 L5:132432 L6:262482
// end 532882 entries (8.5MB). L7 is served by the original hash table.
#define PAIR_BYTES_OFF 262144  // pair region starts 256KB into `out`

__device__ __forceinline__ void level_geom(int l, float& R, int& DIMJ, int& DIMK, int& off4) {
    switch (l) {
        case 0: R=16.f; DIMJ=17; DIMK=16; off4=0;      break;
        case 1: R=20.f; DIMJ=21; DIMK=20; off4=4624;   break;
        case 2: R=25.f; DIMJ=26; DIMK=25; off4=13444;  break;
        case 3: R=32.f; DIMJ=33; DIMK=32; off4=30344;  break;
        case 4: R=40.f; DIMJ=41; DIMK=40; off4=65192;  break;
        case 5: R=50.f; DIMJ=51; DIMK=50; off4=132432; break;
        default:R=64.f; DIMJ=65; DIMK=64; off4=262482; break;
    }
}

// ---------------- kernel 0a: densify coarse tables (float2, for LDS path) --
__global__ __launch_bounds__(256) void densify_kernel(
    const float* __restrict__ tables, float2* __restrict__ dense)
{
    const int lv = (int)blockIdx.y;
    int DIM, E, off;
    if (lv == 0)      { DIM = 17; E = 4913;  off = 0; }
    else if (lv == 1) { DIM = 21; E = 9261;  off = 4913; }
    else              { DIM = 26; E = 17576; off = 14174; }
    const int e = (int)blockIdx.x * 256 + (int)threadIdx.x;
    if (e >= E) return;
    const int d2 = DIM * DIM;
    const int i = e / d2;
    const int rem = e - i * d2;
    const int j = rem / DIM;
    const int k = rem - j * DIM;
    const uint32_t h = ((uint32_t)i ^ ((uint32_t)j * P2) ^ ((uint32_t)k * P3)) & TMASK;
    const float2* __restrict__ tab = (const float2*)tables + (size_t)lv * (size_t)TABLE_SIZE;
    dense[off + e] = tab[h];
}

// ---------------- kernel 0b: densify z-paired tables (float4, levels 0..6) -
// pd[off4 + (i*DIMJ + j)*DIMK + k] = {tab[h(i,j,k)], tab[h(i,j,k+1)]}
__global__ __launch_bounds__(256) void densify_pairs_kernel(
    const float* __restrict__ tables, float4* __restrict__ pd)
{
    const int l = (int)blockIdx.y;          // 0..6
    float R; int DIMJ, DIMK, off4;
    level_geom(l, R, DIMJ, DIMK, off4);
    const int E = (DIMJ * DIMJ) * DIMK;
    const int e = (int)blockIdx.x * 256 + (int)threadIdx.x;
    if (e >= E) return;
    const int jk = DIMJ * DIMK;
    const int i = e / jk;
    const int rem = e - i * jk;
    const int j = rem / DIMK;
    const int k = rem - j * DIMK;
    const uint32_t hb = (uint32_t)i ^ ((uint32_t)j * P2);
    const uint32_t h0 = (hb ^ ((uint32_t)k * P3)) & TMASK;
    const uint32_t h1 = (hb ^ ((uint32_t)(k + 1) * P3)) & TMASK;
    const float2* __restrict__ tab = (const float2*)tables + (size_t)l * (size_t)TABLE_SIZE;
    const float2 a = tab[h0];
    const float2 b = tab[h1];
    pd[off4 + e] = make_float4(a.x, a.y, b.x, b.y);
}

// ---------------- kernel L: LDS-table embed for one coarse level ----------
// 1024 thr/block: L0 39KB x2wg/CU=32 waves, L1 74KB x2=32, L2 140KB x1=16.
__global__ __launch_bounds__(1024) void hash_embed_lds_kernel(
    const float* __restrict__ x, const float2* __restrict__ dense,
    float2* __restrict__ ws, int n, int lv, int DIM, int E, int doff, int ppt)
{
    extern __shared__ float2 lds[];
    for (int e = (int)threadIdx.x; e < E; e += 1024) lds[e] = dense[doff + e];
    __syncthreads();

    const float R = (lv == 0) ? 16.f : (lv == 1) ? 20.f : 25.f;
    const float g = 1.0f / R;
    const int D2 = DIM * DIM;
    const int bmax = DIM - 2;
    float2* __restrict__ wl = ws + (size_t)lv * (size_t)n;
    const int base = (int)blockIdx.x * (1024 * ppt) + (int)threadIdx.x;

#pragma unroll
    for (int p = 0; p < 4; ++p) {
        if (p >= ppt) break;
        const int i = base + p * 1024;
        if (i >= n) break;
        const float px = x[3*i+0], py = x[3*i+1], pz = x[3*i+2];
        const float cx = fminf(fmaxf(px, 0.0f), 1.0f);
        const float cy = fminf(fmaxf(py, 0.0f), 1.0f);
        const float cz = fminf(fmaxf(pz, 0.0f), 1.0f);
        const int bx = min((int)floorf(cx * R), bmax);
        const int by = min((int)floorf(cy * R), bmax);
        const int bz = min((int)floorf(cz * R), bmax);
        const float wx = (px - (float)bx * g) * R;
        const float wy = (py - (float)by * g) * R;
        const float wz = (pz - (float)bz * g) * R;
        const int c = (bx * DIM + by) * DIM + bz;
        const float2 e000 = lds[c];
        const float2 e001 = lds[c + 1];
        const float2 e010 = lds[c + DIM];
        const float2 e011 = lds[c + DIM + 1];
        const float2 e100 = lds[c + D2];
        const float2 e101 = lds[c + D2 + 1];
        const float2 e110 = lds[c + D2 + DIM];
        const float2 e111 = lds[c + D2 + DIM + 1];
        const float omx = 1.0f - wx, omy = 1.0f - wy, omz = 1.0f - wz;
        const float c00a = e000.x*omx + e100.x*wx, c00b = e000.y*omx + e100.y*wx;
        const float c01a = e001.x*omx + e101.x*wx, c01b = e001.y*omx + e101.y*wx;
        const float c10a = e010.x*omx + e110.x*wx, c10b = e010.y*omx + e110.y*wx;
        const float c11a = e011.x*omx + e111.x*wx, c11b = e011.y*omx + e111.y*wx;
        const float c0a = c00a*omy + c10a*wy, c0b = c00b*omy + c10b*wy;
        const float c1a = c01a*omy + c11a*wy, c1b = c01b*omy + c11b*wy;
        float2 r;
        r.x = c0a*omz + c1a*wz;
        r.y = c0b*omz + c1b*wz;
        wl[i] = r;
    }
}

// ---------------- kernel 1: mixed embed (levels lv_base..7) ---------------
// Levels lv_base..6: 4 float4 gathers/point from L2-resident dense pair
// tables. Level 7: 8 float2 gathers from the original 4MB hash table (exact
// per-XCD L2 fit). Level-major block order -> one table active chip-wide.
__global__ __launch_bounds__(256, 4) void hash_embed_mixed_kernel(
    const float* __restrict__ x, const float* __restrict__ tables,
    const float4* __restrict__ pd, float2* __restrict__ ws,
    int n, int lv_base, int bpl)
{
    const int bid = (int)blockIdx.x;
    const int q = bid / bpl;
    const int l = lv_base + q;
    const int pb = bid - q * bpl;
    const int base = pb * 1024 + (int)threadIdx.x;
    if (base >= n) return;

    const int i0 = base, i1 = base + 256, i2 = base + 512, i3 = base + 768;

    const float px0 = x[3*i0+0], py0 = x[3*i0+1], pz0 = x[3*i0+2];
    const float px1 = x[3*i1+0], py1 = x[3*i1+1], pz1 = x[3*i1+2];
    const float px2 = x[3*i2+0], py2 = x[3*i2+1], pz2 = x[3*i2+2];
    const float px3 = x[3*i3+0], py3 = x[3*i3+1], pz3 = x[3*i3+2];

    float2 r0, r1, r2, r3;

    if (l < 7) {
        // ---------------- pair path ----------------
        float R; int DIMJ, DIMK, off4;
        level_geom(l, R, DIMJ, DIMK, off4);
        const float g = 1.0f / R;
        const int bmax = DIMK - 1;           // = R-1
        const int jk = DIMJ * DIMK;
        const float4* __restrict__ tab = pd + off4;

#define PPREP(k) \
        const float cx##k = fminf(fmaxf(px##k, 0.0f), 1.0f); \
        const float cy##k = fminf(fmaxf(py##k, 0.0f), 1.0f); \
        const float cz##k = fminf(fmaxf(pz##k, 0.0f), 1.0f); \
        const int bx##k = min((int)floorf(cx##k * R), bmax); \
        const int by##k = min((int)floorf(cy##k * R), bmax); \
        const int bz##k = min((int)floorf(cz##k * R), bmax); \
        const float wx##k = (px##k - (float)bx##k * g) * R; \
        const float wy##k = (py##k - (float)by##k * g) * R; \
        const float wz##k = (pz##k - (float)bz##k * g) * R; \
        const int c00##k = (bx##k * DIMJ + by##k) * DIMK + bz##k; \
        const int c01##k = c00##k + DIMK; \
        const int c10##k = c00##k + jk; \
        const int c11##k = c10##k + DIMK;

        PPREP(0) PPREP(1) PPREP(2) PPREP(3)

#define PGATHER(k) \
        const float4 d00##k = tab[c00##k]; \
        const float4 d01##k = tab[c01##k]; \
        const float4 d10##k = tab[c10##k]; \
        const float4 d11##k = tab[c11##k];

        PGATHER(0) PGATHER(1) PGATHER(2) PGATHER(3)

        // d00={e000,e001} d01={e010,e011} d10={e100,e101} d11={e110,e111}
#define PINTERP(k, dst) { \
        const float omx = 1.0f - wx##k, omy = 1.0f - wy##k, omz = 1.0f - wz##k; \
        const float c00a = d00##k.x * omx + d10##k.x * wx##k; \
        const float c00b = d00##k.y * omx + d10##k.y * wx##k; \
        const float c01a = d00##k.z * omx + d10##k.z * wx##k; \
        const float c01b = d00##k.w * omx + d10##k.w * wx##k; \
        const float c10a = d01##k.x * omx + d11##k.x * wx##k; \
        const float c10b = d01##k.y * omx + d11##k.y * wx##k; \
        const float c11a = d01##k.z * omx + d11##k.z * wx##k; \
        const float c11b = d01##k.w * omx + d11##k.w * wx##k; \
        const float c0a = c00a * omy + c10a * wy##k; \
        const float c0b = c00b * omy + c10b * wy##k; \
        const float c1a = c01a * omy + c11a * wy##k; \
        const float c1b = c01b * omy + c11b * wy##k; \
        dst.x = c0a * omz + c1a * wz##k; \
        dst.y = c0b * omz + c1b * wz##k; }

        PINTERP(0, r0) PINTERP(1, r1) PINTERP(2, r2) PINTERP(3, r3)
    } else {
        // ---------------- hash path (level 7, R=80) ----------------
        const float R = 80.f;
        const float g = 1.0f / R;
        const float2* __restrict__ tab =
            (const float2*)(tables) + (size_t)7 * (size_t)TABLE_SIZE;

#define HPREP(k) \
        const float cx##k = fminf(fmaxf(px##k, 0.0f), 1.0f); \
        const float cy##k = fminf(fmaxf(py##k, 0.0f), 1.0f); \
        const float cz##k = fminf(fmaxf(pz##k, 0.0f), 1.0f); \
        const int bx##k = (int)floorf(cx##k * R); \
        const int by##k = (int)floorf(cy##k * R); \
        const int bz##k = (int)floorf(cz##k * R); \
        const float wx##k = (px##k - (float)bx##k * g) * R; \
        const float wy##k = (py##k - (float)by##k * g) * R; \
        const float wz##k = (pz##k - (float)bz##k * g) * R; \
        const uint32_t hx0##k = (uint32_t)bx##k; \
        const uint32_t hx1##k = hx0##k + 1u; \
        const uint32_t hy0##k = (uint32_t)by##k * P2; \
        const uint32_t hy1##k = hy0##k + P2; \
        const uint32_t hz0##k = (uint32_t)bz##k * P3; \
        const uint32_t hz1##k = hz0##k + P3;

        HPREP(0) HPREP(1) HPREP(2) HPREP(3)

#define HGATHER(k) \
        const float2 e0##k = tab[(hx0##k ^ hy0##k ^ hz0##k) & TMASK]; \
        const float2 e1##k = tab[(hx0##k ^ hy0##k ^ hz1##k) & TMASK]; \
        const float2 e2##k = tab[(hx0##k ^ hy1##k ^ hz0##k) & TMASK]; \
        const float2 e3##k = tab[(hx0##k ^ hy1##k ^ hz1##k) & TMASK]; \
        const float2 e4##k = tab[(hx1##k ^ hy0##k ^ hz0##k) & TMASK]; \
        const float2 e5##k = tab[(hx1##k ^ hy0##k ^ hz1##k) & TMASK]; \
        const float2 e6##k = tab[(hx1##k ^ hy1##k ^ hz0##k) & TMASK]; \
        const float2 e7##k = tab[(hx1##k ^ hy1##k ^ hz1##k) & TMASK];

        HGATHER(0) HGATHER(1) HGATHER(2) HGATHER(3)

#define HINTERP(k, dst) { \
        const float omx = 1.0f - wx##k, omy = 1.0f - wy##k, omz = 1.0f - wz##k; \
        const float c00a = e0##k.x * omx + e4##k.x * wx##k; \
        const float c00b = e0##k.y * omx + e4##k.y * wx##k; \
        const float c01a = e1##k.x * omx + e5##k.x * wx##k; \
        const float c01b = e1##k.y * omx + e5##k.y * wx##k; \
        const float c10a = e2##k.x * omx + e6##k.x * wx##k; \
        const float c10b = e2##k.y * omx + e6##k.y * wx##k; \
        const float c11a = e3##k.x * omx + e7##k.x * wx##k; \
        const float c11b = e3##k.y * omx + e7##k.y * wx##k; \
        const float c0a = c00a * omy + c10a * wy##k; \
        const float c0b = c00b * omy + c10b * wy##k; \
        const float c1a = c01a * omy + c11a * wy##k; \
        const float c1b = c01b * omy + c11b * wy##k; \
        dst.x = c0a * omz + c1a * wz##k; \
        dst.y = c0b * omz + c1b * wz##k; }

        HINTERP(0, r0) HINTERP(1, r1) HINTERP(2, r2) HINTERP(3, r3)
    }

    float2* __restrict__ wl = ws + (size_t)l * (size_t)n;
    wl[i0] = r0;
    wl[i1] = r1;
    wl[i2] = r2;
    wl[i3] = r3;
}

// ---------------- kernel 2: SoA -> AoS transpose (register-only) ----------
__global__ __launch_bounds__(256) void soa_to_aos_kernel(
    const float2* __restrict__ ws, float* __restrict__ out, int n)
{
    const int i = blockIdx.x * 256 + threadIdx.x;
    if (i >= n) return;

    const float2 v0 = ws[0 * (size_t)n + i];
    const float2 v1 = ws[1 * (size_t)n + i];
    const float2 v2 = ws[2 * (size_t)n + i];
    const float2 v3 = ws[3 * (size_t)n + i];
    const float2 v4 = ws[4 * (size_t)n + i];
    const float2 v5 = ws[5 * (size_t)n + i];
    const float2 v6 = ws[6 * (size_t)n + i];
    const float2 v7 = ws[7 * (size_t)n + i];

    float4* __restrict__ op = (float4*)(out + (size_t)i * 16);
    op[0] = make_float4(v0.x, v0.y, v1.x, v1.y);
    op[1] = make_float4(v2.x, v2.y, v3.x, v3.y);
    op[2] = make_float4(v4.x, v4.y, v5.x, v5.y);
    op[3] = make_float4(v6.x, v6.y, v7.x, v7.y);
}

// ---------------- fallback (ws too small): monolithic ---------------------
__global__ __launch_bounds__(256) void hash_embed_mono_kernel(
    const float* __restrict__ x, const float* __restrict__ tables,
    float* __restrict__ out, int n)
{
    const int i = blockIdx.x * 256 + threadIdx.x;
    if (i >= n) return;
    const float px = x[3*i+0], py = x[3*i+1], pz = x[3*i+2];
    const float cx = fminf(fmaxf(px, 0.0f), 1.0f);
    const float cy = fminf(fmaxf(py, 0.0f), 1.0f);
    const float cz = fminf(fmaxf(pz, 0.0f), 1.0f);
    const float resf[8] = {16.f,20.f,25.f,32.f,40.f,50.f,64.f,80.f};
    float o[16];
#pragma unroll
    for (int l = 0; l < 8; ++l) {
        const float R = resf[l], g = 1.0f / R;
        const int bx = (int)floorf(cx*R), by = (int)floorf(cy*R), bz = (int)floorf(cz*R);
        const float wx = (px - bx*g)*R, wy = (py - by*g)*R, wz = (pz - bz*g)*R;
        const uint32_t hx0 = (uint32_t)bx, hx1 = hx0+1u;
        const uint32_t hy0 = (uint32_t)by*P2, hy1 = hy0+P2;
        const uint32_t hz0 = (uint32_t)bz*P3, hz1 = hz0+P3;
        const float2* tab = (const float2*)(tables) + (size_t)l*(size_t)TABLE_SIZE;
        const float2 e000 = tab[(hx0^hy0^hz0)&TMASK], e001 = tab[(hx0^hy0^hz1)&TMASK];
        const float2 e010 = tab[(hx0^hy1^hz0)&TMASK], e011 = tab[(hx0^hy1^hz1)&TMASK];
        const float2 e100 = tab[(hx1^hy0^hz0)&TMASK], e101 = tab[(hx1^hy0^hz1)&TMASK];
        const float2 e110 = tab[(hx1^hy1^hz0)&TMASK], e111 = tab[(hx1^hy1^hz1)&TMASK];
        const float omx = 1.f-wx, omy = 1.f-wy, omz = 1.f-wz;
        const float c00a = e000.x*omx + e100.x*wx, c00b = e000.y*omx + e100.y*wx;
        const float c01a = e001.x*omx + e101.x*wx, c01b = e001.y*omx + e101.y*wx;
        const float c10a = e010.x*omx + e110.x*wx, c10b = e010.y*omx + e110.y*wx;
        const float c11a = e011.x*omx + e111.x*wx, c11b = e011.y*omx + e111.y*wx;
        const float c0a = c00a*omy + c10a*wy, c0b = c00b*omy + c10b*wy;
        const float c1a = c01a*omy + c11a*wy, c1b = c01b*omy + c11b*wy;
        o[2*l+0] = c0a*omz + c1a*wz;
        o[2*l+1] = c0b*omz + c1b*wz;
    }
    float4* op = (float4*)(out + (size_t)i * 16);
    op[0] = make_float4(o[0],o[1],o[2],o[3]);
    op[1] = make_float4(o[4],o[5],o[6],o[7]);
    op[2] = make_float4(o[8],o[9],o[10],o[11]);
    op[3] = make_float4(o[12],o[13],o[14],o[15]);
}

extern "C" void kernel_launch(void* const* d_in, const int* in_sizes, int n_in,
                              void* d_out, int out_size, void* d_ws, size_t ws_size,
                              hipStream_t stream) {
    const float* x = (const float*)d_in[0];
    const float* tables = (const float*)d_in[1];
    float* out = (float*)d_out;
    const int n = in_sizes[0] / 3;  // 1048576 points

    const size_t ws_needed = (size_t)8 * (size_t)n * sizeof(float2);  // 64 MB
    if (ws_size < ws_needed) {
        hash_embed_mono_kernel<<<(n + 255) / 256, 256, 0, stream>>>(x, tables, out, n);
        return;
    }
    float2* ws = (float2*)d_ws;
    // Scratch in `out` (fully overwritten by soa_to_aos at the end):
    //   [0, 254KB):        float2 coarse dense tables (LDS path)
    //   [256KB, ~8.8MB):   float4 z-paired dense tables (levels 0..6)
    float2* dense = (float2*)out;
    float4* pd = (float4*)((char*)out + PAIR_BYTES_OFF);

    // >64KB dynamic LDS needs opt-in. Cache the capability; degrade gracefully.
    static int nlds = -1;
    if (nlds < 0) {
        if (hipFuncSetAttribute((const void*)hash_embed_lds_kernel,
                hipFuncAttributeMaxDynamicSharedMemorySize, 140608) == hipSuccess)
            nlds = 3;   // levels 0,1,2 via LDS (39/74/140 KB)
        else if (hipFuncSetAttribute((const void*)hash_embed_lds_kernel,
                hipFuncAttributeMaxDynamicSharedMemorySize, 74088) == hipSuccess)
            nlds = 2;   // levels 0,1 via LDS
        else
            nlds = 1;   // level 0 only (39 KB fits default limit)
    }

    // k0a: coarse float2 dense (31,750 gathers). k0b: paired float4 dense for
    // levels 0..6 (532,882 entries, ~1.1M gathers ~= 1/24 of main kernel).
    densify_kernel<<<dim3((17576 + 255) / 256, nlds), 256, 0, stream>>>(tables, dense);
    densify_pairs_kernel<<<dim3((270400 + 255) / 256, 7), 256, 0, stream>>>(tables, pd);

    // LDS-path levels: 1024 thr/block; ppt so grid covers 256 CUs.
    static const int DIMt[3] = {17, 21, 26};
    static const int Et[3]   = {4913, 9261, 17576};
    static const int OFFt[3] = {0, 4913, 14174};
    static const int PPTt[3] = {2, 2, 4};   // grids: 512, 512, 256 blocks
    for (int lv = 0; lv < nlds; ++lv) {
        const int ppb = 1024 * PPTt[lv];
        const int grid = (n + ppb - 1) / ppb;
        hash_embed_lds_kernel<<<grid, 1024, (size_t)Et[lv] * sizeof(float2), stream>>>(
            x, dense, ws, n, lv, DIMt[lv], Et[lv], OFFt[lv], PPTt[lv]);
    }

    // Mixed gather levels nlds..7 (pairs for <7, hash for 7), level-major.
    const int bpl = (n + 1023) / 1024;
    const int nglv = 8 - nlds;
    hash_embed_mixed_kernel<<<bpl * nglv, 256, 0, stream>>>(x, tables, pd, ws, n, nlds, bpl);

    soa_to_aos_kernel<<<(n + 255) / 256, 256, 0, stream>>>(ws, out, n);
}

// Round 8
// 246.300 us; speedup vs baseline: 1.2316x; 1.0734x over previous
//
#include <hip/hip_runtime.h>
#include <hip/hip_fp16.h>
#include <stdint.h>

// HashEmbedder (Instant-NGP hash grid), MI355X gfx950.
// R11 -> R12 (resubmit; R12 bench hit GPUAcquisitionTimeout — never ran).
// R11: 264us total, mixed kernel 102us, FETCH 94MB (L2-residency
// model CONFIRMED). Refined model: the wall is VMEM *instruction* rate
// (~0.5/cyc/CU). Current budget: 24M gathers + 15M scalar x-loads + 5M
// stores = 44M instr. R12 cuts it to ~18M: (a) fp16 tables (x8192 scale,
// pow-2 exact unscale; adds <=3e-8 abs err) -> a 16B entry holds a y*z QUAD
// of corners -> 2 gathers/pt/level for levels<=6 (L6 4.26MB marginal-L2);
// L7 fp16 z-pairs (4.2MB ~exact L2 fit) -> 4 gathers/pt. (b) thread handles
// 4 CONSECUTIVE points: x = 3 float4 loads (0.75 instr/pt vs 3), store = 2
// float4 (0.5 vs 1). Predicted: mixed ~55-75us, total ~220-235us.

#define TABLE_SIZE (1u << 19)
#define TMASK (TABLE_SIZE - 1u)
#define P2 2654435761u
#define P3 805459861u

#define FSCALE 8192.0f
#define FINV   1.220703125e-4f   // 1/8192, exact

// scratch layout inside `out` (64MB, dead after soa_to_aos):
//   [0, 254KB):  f32 coarse dense tables (LDS path, levels 0..2)
//   [256KB, ~8.6MB): fp16 quad tables, levels 0..6 (uint4 entries)
//   [16MB, ~21MB):   fp16 pair table, level 7 (uint2 entries)
#define QUAD_BYTES_OFF 262144
#define PAIR_BYTES_OFF 16777216

// quad tables: entry (i,j,k), i in [0,R] (x corner), j,k in [0,R-1] (y,z cell)
// entry = {h2(j,k), h2(j,k+1), h2(j+1,k), h2(j+1,k+1)}, each h2 = 2 feats fp16
__device__ __forceinline__ void quad_geom(int l, float& R, int& DK, int& offq) {
    switch (l) {
        case 0: R=16.f; DK=16; offq=0;      break;
        case 1: R=20.f; DK=20; offq=4352;   break;
        case 2: R=25.f; DK=25; offq=12752;  break;
        case 3: R=32.f; DK=32; offq=29002;  break;
        case 4: R=40.f; DK=40; offq=62794;  break;
        case 5: R=50.f; DK=50; offq=128394; break;
        default:R=64.f; DK=64; offq=255894; break;  // end 522134 entries
    }
}

__device__ __forceinline__ uint32_t packh2(float a, float b) {
    __half2 h = __floats2half2_rn(a * FSCALE, b * FSCALE);
    uint32_t u;
    *(__half2*)&u = h;
    return u;
}
__device__ __forceinline__ float2 h2f(uint32_t u) {
    __half2 h = *(__half2*)&u;
    return __half22float2(h);
}

// ---------------- kernel 0a: f32 coarse dense (LDS path) ------------------
__global__ __launch_bounds__(256) void densify_kernel(
    const float* __restrict__ tables, float2* __restrict__ dense)
{
    const int lv = (int)blockIdx.y;
    int DIM, E, off;
    if (lv == 0)      { DIM = 17; E = 4913;  off = 0; }
    else if (lv == 1) { DIM = 21; E = 9261;  off = 4913; }
    else              { DIM = 26; E = 17576; off = 14174; }
    const int e = (int)blockIdx.x * 256 + (int)threadIdx.x;
    if (e >= E) return;
    const int d2 = DIM * DIM;
    const int i = e / d2;
    const int rem = e - i * d2;
    const int j = rem / DIM;
    const int k = rem - j * DIM;
    const uint32_t h = ((uint32_t)i ^ ((uint32_t)j * P2) ^ ((uint32_t)k * P3)) & TMASK;
    const float2* __restrict__ tab = (const float2*)tables + (size_t)lv * (size_t)TABLE_SIZE;
    dense[off + e] = tab[h];
}

// ---------------- kernel 0b: fp16 quad tables, levels 0..6 ----------------
__global__ __launch_bounds__(256) void densify_quad_kernel(
    const float* __restrict__ tables, uint4* __restrict__ quads)
{
    const int l = (int)blockIdx.y;          // 0..6
    float R; int DK, offq;
    quad_geom(l, R, DK, offq);
    const int E = (DK + 1) * DK * DK;
    const int e = (int)blockIdx.x * 256 + (int)threadIdx.x;
    if (e >= E) return;
    const int d2 = DK * DK;
    const int i = e / d2;
    const int rem = e - i * d2;
    const int j = rem / DK;
    const int k = rem - j * DK;
    const float2* __restrict__ tab = (const float2*)tables + (size_t)l * (size_t)TABLE_SIZE;
    const uint32_t hx = (uint32_t)i;
    const uint32_t hy0 = (uint32_t)j * P2,       hy1 = hy0 + P2;
    const uint32_t hz0 = (uint32_t)k * P3,       hz1 = hz0 + P3;
    const float2 v00 = tab[(hx ^ hy0 ^ hz0) & TMASK];
    const float2 v01 = tab[(hx ^ hy0 ^ hz1) & TMASK];
    const float2 v10 = tab[(hx ^ hy1 ^ hz0) & TMASK];
    const float2 v11 = tab[(hx ^ hy1 ^ hz1) & TMASK];
    uint4 u;
    u.x = packh2(v00.x, v00.y);
    u.y = packh2(v01.x, v01.y);
    u.z = packh2(v10.x, v10.y);
    u.w = packh2(v11.x, v11.y);
    quads[offq + e] = u;
}

// ---------------- kernel 0c: fp16 pair table, level 7 ---------------------
// entry (i,j,k), i,j in [0,80], k in [0,79]: {h2(z=k), h2(z=k+1)}
__global__ __launch_bounds__(256) void densify_pair7_kernel(
    const float* __restrict__ tables, uint2* __restrict__ pairs)
{
    const int E = 81 * 81 * 80;             // 524,880
    const int e = (int)blockIdx.x * 256 + (int)threadIdx.x;
    if (e >= E) return;
    const int i = e / 6480;                 // 81*80
    const int rem = e - i * 6480;
    const int j = rem / 80;
    const int k = rem - j * 80;
    const float2* __restrict__ tab = (const float2*)tables + (size_t)7 * (size_t)TABLE_SIZE;
    const uint32_t hb = (uint32_t)i ^ ((uint32_t)j * P2);
    const float2 a = tab[(hb ^ ((uint32_t)k * P3)) & TMASK];
    const float2 b = tab[(hb ^ ((uint32_t)(k + 1) * P3)) & TMASK];
    uint2 u;
    u.x = packh2(a.x, a.y);
    u.y = packh2(b.x, b.y);
    pairs[e] = u;
}

// ---------------- kernel L: LDS-table embed (levels 0..2, f32 exact) ------
__global__ __launch_bounds__(1024) void hash_embed_lds_kernel(
    const float* __restrict__ x, const float2* __restrict__ dense,
    float2* __restrict__ ws, int n, int lv, int DIM, int E, int doff, int ppt)
{
    extern __shared__ float2 lds[];
    for (int e = (int)threadIdx.x; e < E; e += 1024) lds[e] = dense[doff + e];
    __syncthreads();

    const float R = (lv == 0) ? 16.f : (lv == 1) ? 20.f : 25.f;
    const float g = 1.0f / R;
    const int D2 = DIM * DIM;
    const int bmax = DIM - 2;
    float2* __restrict__ wl = ws + (size_t)lv * (size_t)n;
    const int base = (int)blockIdx.x * (1024 * ppt) + (int)threadIdx.x;

#pragma unroll
    for (int p = 0; p < 4; ++p) {
        if (p >= ppt) break;
        const int i = base + p * 1024;
        if (i >= n) break;
        const float px = x[3*i+0], py = x[3*i+1], pz = x[3*i+2];
        const float cx = fminf(fmaxf(px, 0.0f), 1.0f);
        const float cy = fminf(fmaxf(py, 0.0f), 1.0f);
        const float cz = fminf(fmaxf(pz, 0.0f), 1.0f);
        const int bx = min((int)floorf(cx * R), bmax);
        const int by = min((int)floorf(cy * R), bmax);
        const int bz = min((int)floorf(cz * R), bmax);
        const float wx = (px - (float)bx * g) * R;
        const float wy = (py - (float)by * g) * R;
        const float wz = (pz - (float)bz * g) * R;
        const int c = (bx * DIM + by) * DIM + bz;
        const float2 e000 = lds[c];
        const float2 e001 = lds[c + 1];
        const float2 e010 = lds[c + DIM];
        const float2 e011 = lds[c + DIM + 1];
        const float2 e100 = lds[c + D2];
        const float2 e101 = lds[c + D2 + 1];
        const float2 e110 = lds[c + D2 + DIM];
        const float2 e111 = lds[c + D2 + DIM + 1];
        const float omx = 1.0f - wx, omy = 1.0f - wy, omz = 1.0f - wz;
        const float c00a = e000.x*omx + e100.x*wx, c00b = e000.y*omx + e100.y*wx;
        const float c01a = e001.x*omx + e101.x*wx, c01b = e001.y*omx + e101.y*wx;
        const float c10a = e010.x*omx + e110.x*wx, c10b = e010.y*omx + e110.y*wx;
        const float c11a = e011.x*omx + e111.x*wx, c11b = e011.y*omx + e111.y*wx;
        const float c0a = c00a*omy + c10a*wy, c0b = c00b*omy + c10b*wy;
        const float c1a = c01a*omy + c11a*wy, c1b = c01b*omy + c11b*wy;
        float2 r;
        r.x = c0a*omz + c1a*wz;
        r.y = c0b*omz + c1b*wz;
        wl[i] = r;
    }
}

// ---------------- single-point helpers (tail path only) -------------------
__device__ float2 embed_quad_one(int l, const uint4* __restrict__ quads,
                                 float px, float py, float pz) {
    float R; int DK, offq;
    quad_geom(l, R, DK, offq);
    const float g = 1.0f / R;
    const int bmax = DK - 1;
    const float cx = fminf(fmaxf(px, 0.0f), 1.0f);
    const float cy = fminf(fmaxf(py, 0.0f), 1.0f);
    const float cz = fminf(fmaxf(pz, 0.0f), 1.0f);
    const int bx = min((int)floorf(cx * R), bmax);
    const int by = min((int)floorf(cy * R), bmax);
    const int bz = min((int)floorf(cz * R), bmax);
    const float wx = (px - (float)bx * g) * R;
    const float wy = (py - (float)by * g) * R;
    const float wz = (pz - (float)bz * g) * R;
    const int d2 = DK * DK;
    const int idx = (bx * DK + by) * DK + bz;
    const uint4 qa = quads[offq + idx];
    const uint4 qb = quads[offq + idx + d2];
    const float omx = 1.0f - wx, omy = 1.0f - wy, omz = 1.0f - wz;
    const float2 a00 = h2f(qa.x), a01 = h2f(qa.y), a10 = h2f(qa.z), a11 = h2f(qa.w);
    const float2 b00 = h2f(qb.x), b01 = h2f(qb.y), b10 = h2f(qb.z), b11 = h2f(qb.w);
    const float m00a = a00.x*omx + b00.x*wx, m00b = a00.y*omx + b00.y*wx;
    const float m01a = a01.x*omx + b01.x*wx, m01b = a01.y*omx + b01.y*wx;
    const float m10a = a10.x*omx + b10.x*wx, m10b = a10.y*omx + b10.y*wx;
    const float m11a = a11.x*omx + b11.x*wx, m11b = a11.y*omx + b11.y*wx;
    const float c0a = m00a*omz + m01a*wz, c0b = m00b*omz + m01b*wz;
    const float c1a = m10a*omz + m11a*wz, c1b = m10b*omz + m11b*wz;
    float2 r;
    r.x = (c0a*omy + c1a*wy) * FINV;
    r.y = (c0b*omy + c1b*wy) * FINV;
    return r;
}
__device__ float2 embed_pair7_one(const uint2* __restrict__ pairs,
                                  float px, float py, float pz) {
    const float R = 80.f, g = 1.0f / R;
    const float cx = fminf(fmaxf(px, 0.0f), 1.0f);
    const float cy = fminf(fmaxf(py, 0.0f), 1.0f);
    const float cz = fminf(fmaxf(pz, 0.0f), 1.0f);
    const int bx = min((int)floorf(cx * R), 79);
    const int by = min((int)floorf(cy * R), 79);
    const int bz = min((int)floorf(cz * R), 79);
    const float wx = (px - (float)bx * g) * R;
    const float wy = (py - (float)by * g) * R;
    const float wz = (pz - (float)bz * g) * R;
    const int idx = (bx * 81 + by) * 80 + bz;
    const uint2 d00 = pairs[idx];
    const uint2 d01 = pairs[idx + 80];
    const uint2 d10 = pairs[idx + 6480];
    const uint2 d11 = pairs[idx + 6560];
    const float omx = 1.0f - wx, omy = 1.0f - wy, omz = 1.0f - wz;
    const float2 a00 = h2f(d00.x), z00 = h2f(d00.y);
    const float2 a01 = h2f(d01.x), z01 = h2f(d01.y);
    const float2 a10 = h2f(d10.x), z10 = h2f(d10.y);
    const float2 a11 = h2f(d11.x), z11 = h2f(d11.y);
    const float c00a = a00.x*omz + z00.x*wz, c00b = a00.y*omz + z00.y*wz;
    const float c01a = a01.x*omz + z01.x*wz, c01b = a01.y*omz + z01.y*wz;
    const float c10a = a10.x*omz + z10.x*wz, c10b = a10.y*omz + z10.y*wz;
    const float c11a = a11.x*omz + z11.x*wz, c11b = a11.y*omz + z11.y*wz;
    const float e0a = c00a*omy + c01a*wy, e0b = c00b*omy + c01b*wy;
    const float e1a = c10a*omy + c11a*wy, e1b = c10b*omy + c11b*wy;
    float2 r;
    r.x = (e0a*omx + e1a*wx) * FINV;
    r.y = (e0b*omx + e1b*wx) * FINV;
    return r;
}

// ---------------- kernel 1: mixed embed (levels lv_base..7) ---------------
// Thread -> 4 consecutive points (vector x loads + stores). Levels <7: 2
// fp16-quad gathers/pt; level 7: 4 fp16-pair gathers/pt. Level-major order.
__global__ __launch_bounds__(256, 4) void hash_embed_mixed_kernel(
    const float* __restrict__ x, const uint4* __restrict__ quads,
    const uint2* __restrict__ pairs, float2* __restrict__ ws,
    int n, int lv_base, int bpl)
{
    const int bid = (int)blockIdx.x;
    const int q = bid / bpl;
    const int l = lv_base + q;
    const int pb = bid - q * bpl;
    const int p0 = pb * 1024 + 4 * (int)threadIdx.x;
    if (p0 >= n) return;

    float2* __restrict__ wl = ws + (size_t)l * (size_t)n;

    if (p0 + 4 > n) {           // rare tail
        for (int pp = 0; pp < 4; ++pp) {
            const int i = p0 + pp;
            if (i >= n) break;
            const float px = x[3*i], py = x[3*i+1], pz = x[3*i+2];
            wl[i] = (l < 7) ? embed_quad_one(l, quads, px, py, pz)
                            : embed_pair7_one(pairs, px, py, pz);
        }
        return;
    }

    // 3 vector loads cover 4 points
    const float4* __restrict__ xv = (const float4*)(x + (size_t)3 * p0);
    const float4 f0 = xv[0], f1 = xv[1], f2 = xv[2];
    const float px0 = f0.x, py0 = f0.y, pz0 = f0.z;
    const float px1 = f0.w, py1 = f1.x, pz1 = f1.y;
    const float px2 = f1.z, py2 = f1.w, pz2 = f2.x;
    const float px3 = f2.y, py3 = f2.z, pz3 = f2.w;

    float2 r0, r1, r2, r3;

    if (l < 7) {
        // ---------------- quad path ----------------
        float R; int DK, offq;
        quad_geom(l, R, DK, offq);
        const float g = 1.0f / R;
        const int bmax = DK - 1;
        const int d2 = DK * DK;
        const uint4* __restrict__ tab = quads + offq;

#define QPREP(k) \
        const float cx##k = fminf(fmaxf(px##k, 0.0f), 1.0f); \
        const float cy##k = fminf(fmaxf(py##k, 0.0f), 1.0f); \
        const float cz##k = fminf(fmaxf(pz##k, 0.0f), 1.0f); \
        const int bx##k = min((int)floorf(cx##k * R), bmax); \
        const int by##k = min((int)floorf(cy##k * R), bmax); \
        const int bz##k = min((int)floorf(cz##k * R), bmax); \
        const float wx##k = (px##k - (float)bx##k * g) * R; \
        const float wy##k = (py##k - (float)by##k * g) * R; \
        const float wz##k = (pz##k - (float)bz##k * g) * R; \
        const int ia##k = (bx##k * DK + by##k) * DK + bz##k; \
        const int ib##k = ia##k + d2;

        QPREP(0) QPREP(1) QPREP(2) QPREP(3)

#define QGATHER(k) \
        const uint4 qa##k = tab[ia##k]; \
        const uint4 qb##k = tab[ib##k];

        QGATHER(0) QGATHER(1) QGATHER(2) QGATHER(3)

#define QINTERP(k, dst) { \
        const float omx = 1.0f - wx##k, omy = 1.0f - wy##k, omz = 1.0f - wz##k; \
        const float2 a00 = h2f(qa##k.x), a01 = h2f(qa##k.y); \
        const float2 a10 = h2f(qa##k.z), a11 = h2f(qa##k.w); \
        const float2 b00 = h2f(qb##k.x), b01 = h2f(qb##k.y); \
        const float2 b10 = h2f(qb##k.z), b11 = h2f(qb##k.w); \
        const float m00a = a00.x*omx + b00.x*wx##k, m00b = a00.y*omx + b00.y*wx##k; \
        const float m01a = a01.x*omx + b01.x*wx##k, m01b = a01.y*omx + b01.y*wx##k; \
        const float m10a = a10.x*omx + b10.x*wx##k, m10b = a10.y*omx + b10.y*wx##k; \
        const float m11a = a11.x*omx + b11.x*wx##k, m11b = a11.y*omx + b11.y*wx##k; \
        const float c0a = m00a*omz + m01a*wz##k, c0b = m00b*omz + m01b*wz##k; \
        const float c1a = m10a*omz + m11a*wz##k, c1b = m10b*omz + m11b*wz##k; \
        dst.x = (c0a*omy + c1a*wy##k) * FINV; \
        dst.y = (c0b*omy + c1b*wy##k) * FINV; }

        QINTERP(0, r0) QINTERP(1, r1) QINTERP(2, r2) QINTERP(3, r3)
    } else {
        // ---------------- pair path (level 7, R=80) ----------------
        const float R = 80.f, g = 1.0f / R;

#define SPREP(k) \
        const float cx##k = fminf(fmaxf(px##k, 0.0f), 1.0f); \
        const float cy##k = fminf(fmaxf(py##k, 0.0f), 1.0f); \
        const float cz##k = fminf(fmaxf(pz##k, 0.0f), 1.0f); \
        const int bx##k = min((int)floorf(cx##k * R), 79); \
        const int by##k = min((int)floorf(cy##k * R), 79); \
        const int bz##k = min((int)floorf(cz##k * R), 79); \
        const float wx##k = (px##k - (float)bx##k * g) * R; \
        const float wy##k = (py##k - (float)by##k * g) * R; \
        const float wz##k = (pz##k - (float)bz##k * g) * R; \
        const int ix##k = (bx##k * 81 + by##k) * 80 + bz##k;

        SPREP(0) SPREP(1) SPREP(2) SPREP(3)

#define SGATHER(k) \
        const uint2 d00##k = pairs[ix##k]; \
        const uint2 d01##k = pairs[ix##k + 80]; \
        const uint2 d10##k = pairs[ix##k + 6480]; \
        const uint2 d11##k = pairs[ix##k + 6560];

        SGATHER(0) SGATHER(1) SGATHER(2) SGATHER(3)

#define SINTERP(k, dst) { \
        const float omx = 1.0f - wx##k, omy = 1.0f - wy##k, omz = 1.0f - wz##k; \
        const float2 a00 = h2f(d00##k.x), z00 = h2f(d00##k.y); \
        const float2 a01 = h2f(d01##k.x), z01 = h2f(d01##k.y); \
        const float2 a10 = h2f(d10##k.x), z10 = h2f(d10##k.y); \
        const float2 a11 = h2f(d11##k.x), z11 = h2f(d11##k.y); \
        const float c00a = a00.x*omz + z00.x*wz##k, c00b = a00.y*omz + z00.y*wz##k; \
        const float c01a = a01.x*omz + z01.x*wz##k, c01b = a01.y*omz + z01.y*wz##k; \
        const float c10a = a10.x*omz + z10.x*wz##k, c10b = a10.y*omz + z10.y*wz##k; \
        const float c11a = a11.x*omz + z11.x*wz##k, c11b = a11.y*omz + z11.y*wz##k; \
        const float e0a = c00a*omy + c01a*wy##k, e0b = c00b*omy + c01b*wy##k; \
        const float e1a = c10a*omy + c11a*wy##k, e1b = c10b*omy + c11b*wy##k; \
        dst.x = (e0a*omx + e1a*wx##k) * FINV; \
        dst.y = (e0b*omx + e1b*wx##k) * FINV; }

        SINTERP(0, r0) SINTERP(1, r1) SINTERP(2, r2) SINTERP(3, r3)
    }

    // 2 vector stores cover 4 consecutive float2
    float4* __restrict__ o = (float4*)(wl + p0);
    o[0] = make_float4(r0.x, r0.y, r1.x, r1.y);
    o[1] = make_float4(r2.x, r2.y, r3.x, r3.y);
}

// ---------------- kernel 2: SoA -> AoS transpose (register-only) ----------
__global__ __launch_bounds__(256) void soa_to_aos_kernel(
    const float2* __restrict__ ws, float* __restrict__ out, int n)
{
    const int i = blockIdx.x * 256 + threadIdx.x;
    if (i >= n) return;

    const float2 v0 = ws[0 * (size_t)n + i];
    const float2 v1 = ws[1 * (size_t)n + i];
    const float2 v2 = ws[2 * (size_t)n + i];
    const float2 v3 = ws[3 * (size_t)n + i];
    const float2 v4 = ws[4 * (size_t)n + i];
    const float2 v5 = ws[5 * (size_t)n + i];
    const float2 v6 = ws[6 * (size_t)n + i];
    const float2 v7 = ws[7 * (size_t)n + i];

    float4* __restrict__ op = (float4*)(out + (size_t)i * 16);
    op[0] = make_float4(v0.x, v0.y, v1.x, v1.y);
    op[1] = make_float4(v2.x, v2.y, v3.x, v3.y);
    op[2] = make_float4(v4.x, v4.y, v5.x, v5.y);
    op[3] = make_float4(v6.x, v6.y, v7.x, v7.y);
}

// ---------------- fallback (ws too small): monolithic, f32 exact ----------
__global__ __launch_bounds__(256) void hash_embed_mono_kernel(
    const float* __restrict__ x, const float* __restrict__ tables,
    float* __restrict__ out, int n)
{
    const int i = blockIdx.x * 256 + threadIdx.x;
    if (i >= n) return;
    const float px = x[3*i+0], py = x[3*i+1], pz = x[3*i+2];
    const float cx = fminf(fmaxf(px, 0.0f), 1.0f);
    const float cy = fminf(fmaxf(py, 0.0f), 1.0f);
    const float cz = fminf(fmaxf(pz, 0.0f), 1.0f);
    const float resf[8] = {16.f,20.f,25.f,32.f,40.f,50.f,64.f,80.f};
    float o[16];
#pragma unroll
    for (int l = 0; l < 8; ++l) {
        const float R = resf[l], g = 1.0f / R;
        const int bx = (int)floorf(cx*R), by = (int)floorf(cy*R), bz = (int)floorf(cz*R);
        const float wx = (px - bx*g)*R, wy = (py - by*g)*R, wz = (pz - bz*g)*R;
        const uint32_t hx0 = (uint32_t)bx, hx1 = hx0+1u;
        const uint32_t hy0 = (uint32_t)by*P2, hy1 = hy0+P2;
        const uint32_t hz0 = (uint32_t)bz*P3, hz1 = hz0+P3;
        const float2* tab = (const float2*)(tables) + (size_t)l*(size_t)TABLE_SIZE;
        const float2 e000 = tab[(hx0^hy0^hz0)&TMASK], e001 = tab[(hx0^hy0^hz1)&TMASK];
        const float2 e010 = tab[(hx0^hy1^hz0)&TMASK], e011 = tab[(hx0^hy1^hz1)&TMASK];
        const float2 e100 = tab[(hx1^hy0^hz0)&TMASK], e101 = tab[(hx1^hy0^hz1)&TMASK];
        const float2 e110 = tab[(hx1^hy1^hz0)&TMASK], e111 = tab[(hx1^hy1^hz1)&TMASK];
        const float omx = 1.f-wx, omy = 1.f-wy, omz = 1.f-wz;
        const float c00a = e000.x*omx + e100.x*wx, c00b = e000.y*omx + e100.y*wx;
        const float c01a = e001.x*omx + e101.x*wx, c01b = e001.y*omx + e101.y*wx;
        const float c10a = e010.x*omx + e110.x*wx, c10b = e010.y*omx + e110.y*wx;
        const float c11a = e011.x*omx + e111.x*wx, c11b = e011.y*omx + e111.y*wx;
        const float c0a = c00a*omy + c10a*wy, c0b = c00b*omy + c10b*wy;
        const float c1a = c01a*omy + c11a*wy, c1b = c01b*omy + c11b*wy;
        o[2*l+0] = c0a*omz + c1a*wz;
        o[2*l+1] = c0b*omz + c1b*wz;
    }
    float4* op = (float4*)(out + (size_t)i * 16);
    op[0] = make_float4(o[0],o[1],o[2],o[3]);
    op[1] = make_float4(o[4],o[5],o[6],o[7]);
    op[2] = make_float4(o[8],o[9],o[10],o[11]);
    op[3] = make_float4(o[12],o[13],o[14],o[15]);
}

extern "C" void kernel_launch(void* const* d_in, const int* in_sizes, int n_in,
                              void* d_out, int out_size, void* d_ws, size_t ws_size,
                              hipStream_t stream) {
    const float* x = (const float*)d_in[0];
    const float* tables = (const float*)d_in[1];
    float* out = (float*)d_out;
    const int n = in_sizes[0] / 3;  // 1048576 points

    const size_t ws_needed = (size_t)8 * (size_t)n * sizeof(float2);  // 64 MB
    if (ws_size < ws_needed) {
        hash_embed_mono_kernel<<<(n + 255) / 256, 256, 0, stream>>>(x, tables, out, n);
        return;
    }
    float2* ws = (float2*)d_ws;
    float2* dense = (float2*)out;
    uint4*  quads = (uint4*)((char*)out + QUAD_BYTES_OFF);
    uint2*  pairs = (uint2*)((char*)out + PAIR_BYTES_OFF);

    // >64KB dynamic LDS needs opt-in. Cache the capability; degrade gracefully.
    static int nlds = -1;
    if (nlds < 0) {
        if (hipFuncSetAttribute((const void*)hash_embed_lds_kernel,
                hipFuncAttributeMaxDynamicSharedMemorySize, 140608) == hipSuccess)
            nlds = 3;   // levels 0,1,2 via LDS (39/74/140 KB)
        else if (hipFuncSetAttribute((const void*)hash_embed_lds_kernel,
                hipFuncAttributeMaxDynamicSharedMemorySize, 74088) == hipSuccess)
            nlds = 2;   // levels 0,1 via LDS
        else
            nlds = 1;   // level 0 only (39 KB fits default limit)
    }

    // table-build kernels (~3.2M gathers total — noise vs 18M main)
    densify_kernel<<<dim3((17576 + 255) / 256, nlds), 256, 0, stream>>>(tables, dense);
    densify_quad_kernel<<<dim3((266240 + 255) / 256, 7), 256, 0, stream>>>(tables, quads);
    densify_pair7_kernel<<<(524880 + 255) / 256, 256, 0, stream>>>(tables, pairs);

    // LDS-path levels: 1024 thr/block.
    static const int DIMt[3] = {17, 21, 26};
    static const int Et[3]   = {4913, 9261, 17576};
    static const int OFFt[3] = {0, 4913, 14174};
    static const int PPTt[3] = {2, 2, 4};   // grids: 512, 512, 256 blocks
    for (int lv = 0; lv < nlds; ++lv) {
        const int ppb = 1024 * PPTt[lv];
        const int grid = (n + ppb - 1) / ppb;
        hash_embed_lds_kernel<<<grid, 1024, (size_t)Et[lv] * sizeof(float2), stream>>>(
            x, dense, ws, n, lv, DIMt[lv], Et[lv], OFFt[lv], PPTt[lv]);
    }

    // Mixed gather levels nlds..7 (fp16 quads <7, fp16 pairs =7), level-major.
    const int bpl = (n + 1023) / 1024;
    const int nglv = 8 - nlds;
    hash_embed_mixed_kernel<<<bpl * nglv, 256, 0, stream>>>(x, quads, pairs, ws, n, nlds, bpl);

    soa_to_aos_kernel<<<(n + 255) / 256, 256, 0, stream>>>(ws, out, n);
}